// Round 1
// baseline (294.847 us; speedup 1.0000x reference)
//
#include <hip/hip_runtime.h>
#include <stdint.h>

typedef __attribute__((ext_vector_type(8))) __bf16 bf16x8;
typedef __attribute__((ext_vector_type(4))) float f32x4;

#define DEV __device__ __forceinline__

#define LOG2E 1.4426950408889634f
#define SCALE 0.17677669529663687f   /* 32^-0.5 */

// sizes
// q_bf:  [256][640][32] bf16 = 10485760 B
// k_bf:  [256][640][32] bf16 = 10485760 B
// vT:    [256][32][640] bf16 = 10485760 B
// O_bf:  [40000][128]   bf16 = 10240000 B
// bias:  [4][625*625]   bf16 =  3125000 B
static constexpr size_t OFF_Q    = 0;
static constexpr size_t OFF_K    = 10485760;
static constexpr size_t OFF_VT   = 20971520;
static constexpr size_t OFF_O    = 31457280;
static constexpr size_t OFF_BIAS = 41697280;

DEV unsigned short f2bf(float f) {
  uint32_t u = __float_as_uint(f);
  u += 0x7fffu + ((u >> 16) & 1u);
  return (unsigned short)(u >> 16);
}
DEV float bf2f(unsigned short s) { return __uint_as_float(((uint32_t)s) << 16); }

DEV bf16x8 cvt8(const float* p) {
  f32x4 a = *(const f32x4*)p;
  f32x4 b = *(const f32x4*)(p + 4);
  bf16x8 r;
  r[0]=(__bf16)a[0]; r[1]=(__bf16)a[1]; r[2]=(__bf16)a[2]; r[3]=(__bf16)a[3];
  r[4]=(__bf16)b[0]; r[5]=(__bf16)b[1]; r[6]=(__bf16)b[2]; r[7]=(__bf16)b[3];
  return r;
}

DEV f32x4 mfma16(bf16x8 a, bf16x8 b, f32x4 c) {
  return __builtin_amdgcn_mfma_f32_16x16x32_bf16(a, b, c, 0, 0, 0);
}

// ---------------------------------------------------------------- K0: zero pads
__global__ __launch_bounds__(256) void k_zero_pads(unsigned short* ws16) {
  int t = blockIdx.x * 256 + threadIdx.x;
  const int PAD1 = 256 * 15 * 32; // 122880 (q and k pad rows n=625..639)
  if (t < PAD1) {
    int bh = t / 480, rem = t % 480;
    int row = 625 + rem / 32, d = rem & 31;
    size_t idx = ((size_t)bh * 640 + row) * 32 + d;
    ws16[OFF_Q / 2 + idx] = 0;
    ws16[OFF_K / 2 + idx] = 0;
  } else {
    t -= PAD1;
    if (t < PAD1) { // vT pad cols
      int bh = t / 480, rem = t % 480;
      int d = rem / 15, col = 625 + rem % 15;
      ws16[OFF_VT / 2 + ((size_t)bh * 32 + d) * 640 + col] = 0;
    }
  }
}

// ---------------------------------------------------------------- K2: bias gather -> bf16 (pre *log2e)
__global__ __launch_bounds__(256) void k_bias(const float* __restrict__ table,
                                              const int* __restrict__ rel,
                                              unsigned short* __restrict__ bias_bf) {
  int t = blockIdx.x * 256 + threadIdx.x;
  if (t >= 625 * 625) return;
  int ri = rel[t];
  #pragma unroll
  for (int h = 0; h < 4; ++h)
    bias_bf[(size_t)h * 390625 + t] = f2bf(table[ri * 4 + h] * LOG2E);
}

// ---------------------------------------------------------------- K1: qkv = x @ W^T + b, repack
__global__ __launch_bounds__(256) void k_qkv(const float* __restrict__ x,
                                             const float* __restrict__ w,
                                             const float* __restrict__ bias,
                                             unsigned short* __restrict__ ws16) {
  int lane = threadIdx.x & 63, wv = threadIdx.x >> 6;
  int g = lane >> 4, l15 = lane & 15;
  int row0 = (blockIdx.x * 4 + wv) * 16;

  bf16x8 a[4];
  #pragma unroll
  for (int ks = 0; ks < 4; ++ks)
    a[ks] = cvt8(x + (size_t)(row0 + l15) * 128 + ks * 32 + g * 8);

  unsigned short* qp = ws16 + OFF_Q / 2;
  unsigned short* kp = ws16 + OFF_K / 2;
  unsigned short* vp = ws16 + OFF_VT / 2;

  #pragma unroll 1
  for (int nf = 0; nf < 24; ++nf) {
    f32x4 acc = {0.f, 0.f, 0.f, 0.f};
    int col = nf * 16 + l15;
    #pragma unroll
    for (int ks = 0; ks < 4; ++ks) {
      bf16x8 bfr = cvt8(w + (size_t)col * 128 + ks * 32 + g * 8);
      acc = mfma16(a[ks], bfr, acc);
    }
    float bv = bias[col];
    int which = nf >> 3;
    int h = (col >> 5) & 3, d = col & 31;
    #pragma unroll
    for (int r = 0; r < 4; ++r) {
      int row = row0 + 4 * g + r;
      int b_ = row / 625;
      int n = row - b_ * 625;
      float v = acc[r] + bv;
      size_t bh = (size_t)b_ * 4 + h;
      if (which == 0)       qp[(bh * 640 + n) * 32 + d] = f2bf(v * (SCALE * LOG2E));
      else if (which == 1)  kp[(bh * 640 + n) * 32 + d] = f2bf(v);
      else                  vp[(bh * 32 + d) * 640 + n] = f2bf(v);
    }
  }
}

// ---------------------------------------------------------------- K3: fused attention
__global__ __launch_bounds__(512) void k_attn(unsigned short* __restrict__ ws16,
                                              const float* __restrict__ mask) {
  __shared__ unsigned short P_lds[8][80 * 40]; // 51200 B, stride 40 bf16 (80 B, 16B-aligned rows)

  int tid = threadIdx.x;
  int lane = tid & 63, wv = tid >> 6;
  int g = lane >> 4, l15 = lane & 15;

  // XCD-aware decode: the 8 (outer,h) blocks sharing mask[w] land on one XCD
  int bid = blockIdx.x;
  int xcd = bid & 7, slot = bid >> 3;
  int bh8 = slot & 7, wgrp = slot >> 3;
  int w = wgrp * 8 + xcd;
  int h = bh8 & 3, outer = bh8 >> 2;
  int b = outer * 32 + w;
  size_t bh = (size_t)b * 4 + h;

  const unsigned short* qp = ws16 + OFF_Q / 2 + bh * 640 * 32;
  const unsigned short* kp = ws16 + OFF_K / 2 + bh * 640 * 32;
  const unsigned short* vp = ws16 + OFF_VT / 2 + bh * 32 * 640;
  const unsigned short* biasp = ws16 + OFF_BIAS / 2 + (size_t)h * 390625;
  const float* maskp = mask + (size_t)w * 390625;
  int q0 = wv * 80;

  bf16x8 aq[5];
  #pragma unroll
  for (int mf = 0; mf < 5; ++mf)
    aq[mf] = *(const bf16x8*)(qp + (size_t)(q0 + mf * 16 + l15) * 32 + g * 8);

  f32x4 O[5][2];
  float mrow[5][4], lrow[5][4];
  #pragma unroll
  for (int mf = 0; mf < 5; ++mf) {
    #pragma unroll
    for (int r = 0; r < 4; ++r) { mrow[mf][r] = -3.0e38f; lrow[mf][r] = 0.f; }
    O[mf][0] = (f32x4){0.f, 0.f, 0.f, 0.f};
    O[mf][1] = (f32x4){0.f, 0.f, 0.f, 0.f};
  }

  #pragma unroll 1
  for (int jt = 0; jt < 10; ++jt) {
    int j0 = jt * 64;
    // ---- S = Q K^T (pre-scaled by scale*log2e)
    f32x4 S[5][4];
    #pragma unroll
    for (int nf = 0; nf < 4; ++nf) {
      bf16x8 bk = *(const bf16x8*)(kp + (size_t)(j0 + nf * 16 + l15) * 32 + g * 8);
      #pragma unroll
      for (int mf = 0; mf < 5; ++mf)
        S[mf][nf] = mfma16(aq[mf], bk, (f32x4){0.f, 0.f, 0.f, 0.f});
    }
    // ---- + bias*log2e + mask*log2e  (pad cols j>=625 -> -1e30)
    #pragma unroll
    for (int mf = 0; mf < 5; ++mf) {
      #pragma unroll
      for (int r = 0; r < 4; ++r) {
        int i = q0 + mf * 16 + 4 * g + r;
        int ir = i < 625 ? i : 624;
        size_t rowoff = (size_t)ir * 625;
        #pragma unroll
        for (int nf = 0; nf < 4; ++nf) {
          int j = j0 + nf * 16 + l15;
          int jc = j < 625 ? j : 624;
          float mv = maskp[rowoff + jc];
          float bvv = bf2f(biasp[rowoff + jc]);
          float bm = (j < 625) ? fmaf(mv, LOG2E, bvv) : -1.0e30f;
          S[mf][nf][r] += bm;
        }
      }
    }
    // ---- online softmax: row max, rescale
    float corr[5][4];
    #pragma unroll
    for (int mf = 0; mf < 5; ++mf) {
      #pragma unroll
      for (int r = 0; r < 4; ++r) {
        float t = fmaxf(fmaxf(S[mf][0][r], S[mf][1][r]), fmaxf(S[mf][2][r], S[mf][3][r]));
        t = fmaxf(t, __shfl_xor(t, 1, 16));
        t = fmaxf(t, __shfl_xor(t, 2, 16));
        t = fmaxf(t, __shfl_xor(t, 4, 16));
        t = fmaxf(t, __shfl_xor(t, 8, 16));
        float mn = fmaxf(mrow[mf][r], t);
        float c = exp2f(mrow[mf][r] - mn);
        corr[mf][r] = c;
        mrow[mf][r] = mn;
        lrow[mf][r] *= c;
      }
    }
    #pragma unroll
    for (int mf = 0; mf < 5; ++mf)
      #pragma unroll
      for (int nn = 0; nn < 2; ++nn)
        #pragma unroll
        for (int r = 0; r < 4; ++r)
          O[mf][nn][r] *= corr[mf][r];

    float rs[5][4];
    #pragma unroll
    for (int mf = 0; mf < 5; ++mf)
      #pragma unroll
      for (int r = 0; r < 4; ++r) rs[mf][r] = 0.f;

    // ---- P = exp2(S - m); PV in two k-halves through per-wave LDS
    #pragma unroll
    for (int half = 0; half < 2; ++half) {
      asm volatile("s_waitcnt lgkmcnt(0)" ::: "memory"); // WAR vs previous reads
      #pragma unroll
      for (int nf2 = 0; nf2 < 2; ++nf2) {
        int nf = half * 2 + nf2;
        #pragma unroll
        for (int mf = 0; mf < 5; ++mf) {
          #pragma unroll
          for (int r = 0; r < 4; ++r) {
            float p = exp2f(S[mf][nf][r] - mrow[mf][r]);
            rs[mf][r] += p;
            P_lds[wv][(mf * 16 + 4 * g + r) * 40 + nf2 * 16 + l15] = f2bf(p);
          }
        }
      }
      asm volatile("s_waitcnt lgkmcnt(0)" ::: "memory"); // RAW: writes visible
      bf16x8 bv0 = *(const bf16x8*)(vp + (size_t)(l15) * 640 + j0 + half * 32 + g * 8);
      bf16x8 bv1 = *(const bf16x8*)(vp + (size_t)(16 + l15) * 640 + j0 + half * 32 + g * 8);
      #pragma unroll
      for (int mf = 0; mf < 5; ++mf) {
        bf16x8 pa = *(const bf16x8*)(&P_lds[wv][(mf * 16 + l15) * 40 + g * 8]);
        O[mf][0] = mfma16(pa, bv0, O[mf][0]);
        O[mf][1] = mfma16(pa, bv1, O[mf][1]);
      }
    }
    // ---- l update
    #pragma unroll
    for (int mf = 0; mf < 5; ++mf) {
      #pragma unroll
      for (int r = 0; r < 4; ++r) {
        float s = rs[mf][r];
        s += __shfl_xor(s, 1, 16);
        s += __shfl_xor(s, 2, 16);
        s += __shfl_xor(s, 4, 16);
        s += __shfl_xor(s, 8, 16);
        lrow[mf][r] += s;
      }
    }
  }

  // ---- normalize + write O_bf (B*N, 128) bf16
  unsigned short* obf = ws16 + OFF_O / 2;
  #pragma unroll
  for (int mf = 0; mf < 5; ++mf) {
    #pragma unroll
    for (int r = 0; r < 4; ++r) {
      int n = q0 + mf * 16 + 4 * g + r;
      if (n < 625) {
        float inv = 1.0f / lrow[mf][r];
        size_t base = ((size_t)b * 625 + n) * 128 + h * 32;
        obf[base + l15]      = f2bf(O[mf][0][r] * inv);
        obf[base + 16 + l15] = f2bf(O[mf][1][r] * inv);
      }
    }
  }
}

// ---------------------------------------------------------------- K4: out = O @ proj_w^T + b (fp32 out)
__global__ __launch_bounds__(256) void k_proj(const unsigned short* __restrict__ ws16,
                                              const float* __restrict__ w,
                                              const float* __restrict__ bias,
                                              float* __restrict__ out) {
  int lane = threadIdx.x & 63, wv = threadIdx.x >> 6;
  int g = lane >> 4, l15 = lane & 15;
  int row0 = (blockIdx.x * 4 + wv) * 16;
  const unsigned short* obf = ws16 + OFF_O / 2;

  bf16x8 a[4];
  #pragma unroll
  for (int ks = 0; ks < 4; ++ks)
    a[ks] = *(const bf16x8*)(obf + (size_t)(row0 + l15) * 128 + ks * 32 + g * 8);

  #pragma unroll 1
  for (int nf = 0; nf < 8; ++nf) {
    f32x4 acc = {0.f, 0.f, 0.f, 0.f};
    int col = nf * 16 + l15;
    #pragma unroll
    for (int ks = 0; ks < 4; ++ks) {
      bf16x8 bfr = cvt8(w + (size_t)col * 128 + ks * 32 + g * 8);
      acc = mfma16(a[ks], bfr, acc);
    }
    float bv = bias[col];
    #pragma unroll
    for (int r = 0; r < 4; ++r)
      out[(size_t)(row0 + 4 * g + r) * 128 + col] = acc[r] + bv;
  }
}

// ----------------------------------------------------------------
extern "C" void kernel_launch(void* const* d_in, const int* in_sizes, int n_in,
                              void* d_out, int out_size, void* d_ws, size_t ws_size,
                              hipStream_t stream) {
  (void)in_sizes; (void)n_in; (void)out_size; (void)ws_size;
  const float* x      = (const float*)d_in[0];
  const float* mask   = (const float*)d_in[1];
  const float* qkv_w  = (const float*)d_in[2];
  const float* qkv_b  = (const float*)d_in[3];
  const float* proj_w = (const float*)d_in[4];
  const float* proj_b = (const float*)d_in[5];
  const float* table  = (const float*)d_in[6];
  const int*   rel    = (const int*)d_in[7];
  unsigned short* ws16 = (unsigned short*)d_ws;
  float* out = (float*)d_out;

  k_zero_pads<<<960, 256, 0, stream>>>(ws16);
  k_bias<<<1526, 256, 0, stream>>>(table, rel, ws16 + OFF_BIAS / 2);
  k_qkv<<<625, 256, 0, stream>>>(x, qkv_w, qkv_b, ws16);
  k_attn<<<256, 512, 0, stream>>>(ws16, mask);
  k_proj<<<625, 256, 0, stream>>>(ws16, proj_w, proj_b, out);
}

// Round 2
// 237.081 us; speedup vs baseline: 1.2437x; 1.2437x over previous
//
#include <hip/hip_runtime.h>
#include <stdint.h>

typedef __attribute__((ext_vector_type(8))) __bf16 bf16x8;
typedef __attribute__((ext_vector_type(4))) __bf16 bf16x4;
typedef __attribute__((ext_vector_type(4))) float f32x4;

#define DEV __device__ __forceinline__
#define LOG2E 1.4426950408889634f
#define SCALE 0.17677669529663687f   /* 32^-0.5 */

// ws layout (bytes)
static constexpr size_t OFF_Q     = 0;          // [256 bh][640 n][32 d] bf16, q pre-scaled by SCALE*LOG2E
static constexpr size_t OFF_K     = 10485760;   // [256][640][32] bf16
static constexpr size_t OFF_VT    = 20971520;   // [256][32 d][640 n] bf16
static constexpr size_t OFF_O     = 31457280;   // [40000][128] bf16
static constexpr size_t OFF_BIASP = 41697280;   // [4 h][640 i][640 j] bf16, *LOG2E, pad=0
static constexpr size_t OFF_WBF   = 44974080;   // qkv_w bf16 (49152 el) then proj_w bf16 (16384 el)
static constexpr size_t OFF_MASKP = 45105152;   // [32 w][640 i][640 j] fp32, *LOG2E, pad=-1e30
static constexpr size_t WS_FULL   = 97533952;

DEV bf16x8 cvt8(const float* p) {
  f32x4 a = *(const f32x4*)p;
  f32x4 b = *(const f32x4*)(p + 4);
  bf16x8 r;
  r[0]=(__bf16)a[0]; r[1]=(__bf16)a[1]; r[2]=(__bf16)a[2]; r[3]=(__bf16)a[3];
  r[4]=(__bf16)b[0]; r[5]=(__bf16)b[1]; r[6]=(__bf16)b[2]; r[7]=(__bf16)b[3];
  return r;
}

DEV f32x4 mfma16(bf16x8 a, bf16x8 b, f32x4 c) {
  return __builtin_amdgcn_mfma_f32_16x16x32_bf16(a, b, c, 0, 0, 0);
}

// ---------------------------------------------------------------- zero pad rows/cols of q,k,vT
__global__ __launch_bounds__(256) void k_zero_pads(__bf16* ws_q, __bf16* ws_k, __bf16* ws_v) {
  int t = blockIdx.x * 256 + threadIdx.x;
  const int PAD1 = 256 * 15 * 32; // q,k pad rows n=625..639
  if (t < PAD1) {
    int bh = t / 480, rem = t % 480;
    int row = 625 + rem / 32, d = rem & 31;
    size_t idx = ((size_t)bh * 640 + row) * 32 + d;
    ws_q[idx] = (__bf16)0.f;
    ws_k[idx] = (__bf16)0.f;
  } else {
    t -= PAD1;
    if (t < PAD1) { // vT pad cols
      int bh = t / 480, rem = t % 480;
      int d = rem / 15, col = 625 + rem % 15;
      ws_v[((size_t)bh * 32 + d) * 640 + col] = (__bf16)0.f;
    }
  }
}

// ---------------------------------------------------------------- weights -> bf16 (once)
__global__ __launch_bounds__(256) void k_wconv(const float* __restrict__ wq,
                                               const float* __restrict__ wp,
                                               __bf16* __restrict__ dst) {
  int t = blockIdx.x * 256 + threadIdx.x; // 65536 total
  if (t < 49152) dst[t] = (__bf16)wq[t];
  else           dst[t] = (__bf16)wp[t - 49152];
}

// ---------------------------------------------------------------- biasPad: [h][640][640] bf16, *LOG2E
__global__ __launch_bounds__(256) void k_biaspad(const float* __restrict__ table,
                                                 const int* __restrict__ rel,
                                                 __bf16* __restrict__ bp) {
  int t = blockIdx.x * 256 + threadIdx.x; // 4*640*160 = 409600
  int h = t / 102400, rem = t % 102400;
  int i = rem / 160, j4 = (rem % 160) * 4;
  bf16x4 v;
  if (i < 625) {
    #pragma unroll
    for (int r = 0; r < 4; ++r) {
      int j = j4 + r;
      v[r] = (j < 625) ? (__bf16)(table[(size_t)rel[(size_t)i * 625 + j] * 4 + h] * LOG2E)
                       : (__bf16)0.f;
    }
  } else {
    v[0] = v[1] = v[2] = v[3] = (__bf16)0.f;
  }
  *(bf16x4*)(bp + ((size_t)h * 640 + i) * 640 + j4) = v;
}

// ---------------------------------------------------------------- maskPad: [w][640][640] fp32, *LOG2E, pad=-1e30
__global__ __launch_bounds__(256) void k_maskpad(const float* __restrict__ mask,
                                                 float* __restrict__ mp) {
  int t = blockIdx.x * 256 + threadIdx.x; // 32*640*160 = 3276800
  int w = t / 102400, rem = t % 102400;
  int i = rem / 160, j4 = (rem % 160) * 4;
  f32x4 v;
  if (i < 625) {
    const float* src = mask + (size_t)w * 390625 + (size_t)i * 625;
    #pragma unroll
    for (int r = 0; r < 4; ++r) {
      int j = j4 + r;
      v[r] = (j < 625) ? src[j] * LOG2E : -1.0e30f;
    }
  } else {
    v[0] = v[1] = v[2] = v[3] = -1.0e30f;
  }
  *(f32x4*)(mp + ((size_t)w * 640 + i) * 640 + j4) = v;
}

// ---------------------------------------------------------------- qkv = x @ W^T + b, repack per-head
__global__ __launch_bounds__(256) void k_qkv(const float* __restrict__ x,
                                             const __bf16* __restrict__ wbf,
                                             const float* __restrict__ bias,
                                             __bf16* __restrict__ qp,
                                             __bf16* __restrict__ kp,
                                             __bf16* __restrict__ vp) {
  int lane = threadIdx.x & 63, wv = threadIdx.x >> 6;
  int g = lane >> 4, l15 = lane & 15;
  int row0 = (blockIdx.x * 4 + wv) * 16;

  bf16x8 a[4];
  #pragma unroll
  for (int ks = 0; ks < 4; ++ks)
    a[ks] = cvt8(x + (size_t)(row0 + l15) * 128 + ks * 32 + g * 8);

  #pragma unroll 1
  for (int nf = 0; nf < 24; ++nf) {
    f32x4 acc = {0.f, 0.f, 0.f, 0.f};
    int col = nf * 16 + l15;
    #pragma unroll
    for (int ks = 0; ks < 4; ++ks) {
      bf16x8 bfr = *(const bf16x8*)(wbf + (size_t)col * 128 + ks * 32 + g * 8);
      acc = mfma16(a[ks], bfr, acc);
    }
    float bv = bias[col];
    int which = nf >> 3;
    int h = (col >> 5) & 3, d = col & 31;
    #pragma unroll
    for (int r = 0; r < 4; ++r) {
      int row = row0 + 4 * g + r;
      int b_ = row / 625;
      int n = row - b_ * 625;
      float v = acc[r] + bv;
      size_t bh = (size_t)b_ * 4 + h;
      if (which == 0)       qp[(bh * 640 + n) * 32 + d] = (__bf16)(v * (SCALE * LOG2E));
      else if (which == 1)  kp[(bh * 640 + n) * 32 + d] = (__bf16)v;
      else                  vp[(bh * 32 + d) * 640 + n] = (__bf16)v;
    }
  }
}

// ---------------------------------------------------------------- fused attention, S^T orientation
// grid 512 blocks x 320 threads (5 waves); each wave owns 64 q-rows, sweeps j in 32-tiles.
template<bool PADDED>
__global__ __launch_bounds__(320, 3) void k_attn2(const __bf16* __restrict__ qball,
                                                  const __bf16* __restrict__ kball,
                                                  const __bf16* __restrict__ vball,
                                                  __bf16* __restrict__ oball,
                                                  const __bf16* __restrict__ biasp,
                                                  const float* __restrict__ maskp,
                                                  const float* __restrict__ maskraw) {
  __shared__ __align__(16) unsigned short Pl[5][64 * 40]; // 25600 B, row stride 40 bf16 = 80 B

  int tid = threadIdx.x;
  int lane = tid & 63, wv = tid >> 6;
  int g = lane >> 4, l15 = lane & 15;

  // XCD-aware decode: the 16 blocks sharing mask[w] land on one XCD
  int bid = blockIdx.x;
  int xcd = bid & 7, slot = bid >> 3;        // slot 0..63
  int w = xcd + 8 * (slot & 3);
  int rem = slot >> 2;                       // 0..15
  int h = rem & 3, o = (rem >> 2) & 1, half = rem >> 3;
  int b = o * 32 + w;
  size_t bh = (size_t)b * 4 + h;

  const __bf16* qp = qball + bh * (640 * 32);
  const __bf16* kp = kball + bh * (640 * 32);
  const __bf16* vp = vball + bh * (32 * 640);
  const __bf16* brow = biasp + (size_t)h * (640 * 640);
  const float*  mrowP = maskp + (size_t)w * (640 * 640);
  const float*  mrowR = maskraw + (size_t)w * 390625;

  int q0 = half * 320 + wv * 64;

  bf16x8 aq[4];
  #pragma unroll
  for (int mf = 0; mf < 4; ++mf)
    aq[mf] = *(const bf16x8*)(qp + (size_t)(q0 + mf * 16 + l15) * 32 + g * 8);

  f32x4 O[4][2];
  float m[4], l[4];
  #pragma unroll
  for (int mf = 0; mf < 4; ++mf) {
    O[mf][0] = (f32x4){0.f, 0.f, 0.f, 0.f};
    O[mf][1] = (f32x4){0.f, 0.f, 0.f, 0.f};
    m[mf] = -1.0e30f; l[mf] = 0.f;
  }

  unsigned short* Prow[4];
  #pragma unroll
  for (int mf = 0; mf < 4; ++mf)
    Prow[mf] = &Pl[wv][(mf * 16 + l15) * 40];

  #pragma unroll 1
  for (int jt = 0; jt < 20; ++jt) {
    int j0 = jt * 32;
    bf16x8 bk0 = *(const bf16x8*)(kp + (size_t)(j0 + l15) * 32 + g * 8);
    bf16x8 bk1 = *(const bf16x8*)(kp + (size_t)(j0 + 16 + l15) * 32 + g * 8);

    // ---- S^T = K Q^T with C preloaded with bias+mask (log2-scaled)
    f32x4 S[4][2];
    #pragma unroll
    for (int mf = 0; mf < 4; ++mf) {
      int i = q0 + mf * 16 + l15;
      #pragma unroll
      for (int nf = 0; nf < 2; ++nf) {
        int jb = j0 + nf * 16 + 4 * g;
        f32x4 c;
        if constexpr (PADDED) {
          bf16x4 bv4 = *(const bf16x4*)(brow + (size_t)i * 640 + jb);
          f32x4 mv = *(const f32x4*)(mrowP + (size_t)i * 640 + jb);
          #pragma unroll
          for (int r = 0; r < 4; ++r) c[r] = mv[r] + (float)bv4[r];
        } else {
          int ir = i < 625 ? i : 624;
          bf16x4 bv4 = *(const bf16x4*)(brow + (size_t)ir * 640 + jb);
          const float* mr = mrowR + (size_t)ir * 625;
          #pragma unroll
          for (int r = 0; r < 4; ++r) {
            int j = jb + r;
            float mval = mr[j < 625 ? j : 624];
            c[r] = (j < 625) ? fmaf(mval, LOG2E, (float)bv4[r]) : -1.0e30f;
          }
        }
        S[mf][nf] = mfma16(nf ? bk1 : bk0, aq[mf], c);
      }
    }

    // ---- online softmax (per-lane i = l15), write P to LDS, rescale O
    #pragma unroll
    for (int mf = 0; mf < 4; ++mf) {
      float t = fmaxf(fmaxf(fmaxf(S[mf][0][0], S[mf][0][1]), fmaxf(S[mf][0][2], S[mf][0][3])),
                      fmaxf(fmaxf(S[mf][1][0], S[mf][1][1]), fmaxf(S[mf][1][2], S[mf][1][3])));
      t = fmaxf(t, __shfl_xor(t, 16));
      t = fmaxf(t, __shfl_xor(t, 32));
      float mn = fmaxf(m[mf], t);
      float corr = exp2f(m[mf] - mn);
      m[mf] = mn;

      float ps = 0.f;
      bf16x4 pk0, pk1;
      #pragma unroll
      for (int r = 0; r < 4; ++r) {
        float p0 = exp2f(S[mf][0][r] - mn);
        float p1 = exp2f(S[mf][1][r] - mn);
        ps += p0 + p1;
        pk0[r] = (__bf16)p0;
        pk1[r] = (__bf16)p1;
      }
      ps += __shfl_xor(ps, 16);
      ps += __shfl_xor(ps, 32);
      l[mf] = l[mf] * corr + ps;

      *(bf16x4*)(Prow[mf] + 4 * g) = pk0;        // col nf*16 + 4g
      *(bf16x4*)(Prow[mf] + 16 + 4 * g) = pk1;

      // redistribute corr from lane l15=i to lane layout i=4g+r
      f32x4 cr;
      #pragma unroll
      for (int r = 0; r < 4; ++r) cr[r] = __shfl(corr, 4 * g + r);
      O[mf][0] *= cr;
      O[mf][1] *= cr;
    }

    // ---- PV: O += P V  (A-frag from LDS, B-frag from vT)
    bf16x8 bv0 = *(const bf16x8*)(vp + (size_t)l15 * 640 + j0 + 8 * g);
    bf16x8 bv1 = *(const bf16x8*)(vp + (size_t)(16 + l15) * 640 + j0 + 8 * g);
    #pragma unroll
    for (int mf = 0; mf < 4; ++mf) {
      bf16x8 pa = *(const bf16x8*)(Prow[mf] + 8 * g);
      O[mf][0] = mfma16(pa, bv0, O[mf][0]);
      O[mf][1] = mfma16(pa, bv1, O[mf][1]);
    }
  }

  // ---- normalize + store O_bf
  #pragma unroll
  for (int mf = 0; mf < 4; ++mf) {
    float inv = 1.0f / l[mf];
    f32x4 ivr;
    #pragma unroll
    for (int r = 0; r < 4; ++r) ivr[r] = __shfl(inv, 4 * g + r);
    #pragma unroll
    for (int r = 0; r < 4; ++r) {
      int i = q0 + mf * 16 + 4 * g + r;
      if (i < 625) {
        size_t base = ((size_t)b * 625 + i) * 128 + h * 32;
        oball[base + l15]      = (__bf16)(O[mf][0][r] * ivr[r]);
        oball[base + 16 + l15] = (__bf16)(O[mf][1][r] * ivr[r]);
      }
    }
  }
}

// ---------------------------------------------------------------- out = O @ proj_w^T + b (fp32)
__global__ __launch_bounds__(256) void k_proj(const __bf16* __restrict__ obf,
                                              const __bf16* __restrict__ wbf,
                                              const float* __restrict__ bias,
                                              float* __restrict__ out) {
  int lane = threadIdx.x & 63, wv = threadIdx.x >> 6;
  int g = lane >> 4, l15 = lane & 15;
  int row0 = (blockIdx.x * 4 + wv) * 16;

  bf16x8 a[4];
  #pragma unroll
  for (int ks = 0; ks < 4; ++ks)
    a[ks] = *(const bf16x8*)(obf + (size_t)(row0 + l15) * 128 + ks * 32 + g * 8);

  #pragma unroll 1
  for (int nf = 0; nf < 8; ++nf) {
    f32x4 acc = {0.f, 0.f, 0.f, 0.f};
    int col = nf * 16 + l15;
    #pragma unroll
    for (int ks = 0; ks < 4; ++ks) {
      bf16x8 bfr = *(const bf16x8*)(wbf + (size_t)col * 128 + ks * 32 + g * 8);
      acc = mfma16(a[ks], bfr, acc);
    }
    float bv = bias[col];
    #pragma unroll
    for (int r = 0; r < 4; ++r)
      out[(size_t)(row0 + 4 * g + r) * 128 + col] = acc[r] + bv;
  }
}

// ----------------------------------------------------------------
extern "C" void kernel_launch(void* const* d_in, const int* in_sizes, int n_in,
                              void* d_out, int out_size, void* d_ws, size_t ws_size,
                              hipStream_t stream) {
  (void)in_sizes; (void)n_in; (void)out_size;
  const float* x      = (const float*)d_in[0];
  const float* mask   = (const float*)d_in[1];
  const float* qkv_w  = (const float*)d_in[2];
  const float* qkv_b  = (const float*)d_in[3];
  const float* proj_w = (const float*)d_in[4];
  const float* proj_b = (const float*)d_in[5];
  const float* table  = (const float*)d_in[6];
  const int*   rel    = (const int*)d_in[7];
  char* ws = (char*)d_ws;
  float* out = (float*)d_out;

  __bf16* qp    = (__bf16*)(ws + OFF_Q);
  __bf16* kp    = (__bf16*)(ws + OFF_K);
  __bf16* vp    = (__bf16*)(ws + OFF_VT);
  __bf16* obf   = (__bf16*)(ws + OFF_O);
  __bf16* biasp = (__bf16*)(ws + OFF_BIASP);
  __bf16* wbf   = (__bf16*)(ws + OFF_WBF);
  float*  maskp = (float*)(ws + OFF_MASKP);

  bool padded = ws_size >= WS_FULL;

  k_zero_pads<<<960, 256, 0, stream>>>(qp, kp, vp);
  k_wconv<<<256, 256, 0, stream>>>(qkv_w, proj_w, wbf);
  k_biaspad<<<1600, 256, 0, stream>>>(table, rel, biasp);
  if (padded) k_maskpad<<<12800, 256, 0, stream>>>(mask, maskp);
  k_qkv<<<625, 256, 0, stream>>>(x, wbf, qkv_b, qp, kp, vp);
  if (padded) k_attn2<true><<<512, 320, 0, stream>>>(qp, kp, vp, obf, biasp, maskp, mask);
  else        k_attn2<false><<<512, 320, 0, stream>>>(qp, kp, vp, obf, biasp, maskp, mask);
  k_proj<<<625, 256, 0, stream>>>(obf, wbf + 49152, proj_b, out);
}